// Round 11
// baseline (229.845 us; speedup 1.0000x reference)
//
#include <hip/hip_runtime.h>

#define N_USERS 100000
#define N_ITEMS 50000
#define NROWS (N_USERS + N_ITEMS)
#define EMB 64
#define N_EDGES 1000000

// ---- bucketed CSR build parameters ----
#define SH_U 9                 // 512 users per bucket
#define SH_I 8                 // 256 items per bucket
#define NBUK 196
#define B1 256
#define CHUNK ((N_EDGES + B1 - 1) / B1)   // 3907
#define HN (2 * NBUK * B1)
#define HTILE 4096
#define HTILES ((HN + HTILE - 1) / HTILE) // 25
#define DBINS 64

// gather schedule: 4688 slot-chunks = 8 XCD regions x 586
#define GCHUNKS 4688
#define XREG 586

typedef unsigned short u16;
typedef u16 us8 __attribute__((ext_vector_type(8)));
typedef u16 us4 __attribute__((ext_vector_type(4)));
typedef float f4 __attribute__((ext_vector_type(4)));

static __device__ __forceinline__ float bf2f(u16 h) {
    return __uint_as_float(((unsigned)h) << 16);
}
static __device__ __forceinline__ u16 f2bf(float f) {
    unsigned u = __float_as_uint(f);
    return (u16)((u + 0x7FFFu + ((u >> 16) & 1u)) >> 16);
}

static __device__ __forceinline__ int hphys(int L) {
    int sb = L >> 8;
    int blk = L & 255;
    return blk * (2 * NBUK) + sb;
}

// f32 -> bf16, both tables in one launch
__global__ void conv_kernel(const float* __restrict__ ua, u16* __restrict__ ub,
                            const float* __restrict__ ia, u16* __restrict__ ib) {
    const int un4 = N_USERS * EMB / 4;
    const int in4 = N_ITEMS * EMB / 4;
    int t = blockIdx.x * blockDim.x + threadIdx.x;
    const float* a; u16* b; int idx;
    if (t < un4) { a = ua; b = ub; idx = t; }
    else if (t < un4 + in4) { a = ia; b = ib; idx = t - un4; }
    else return;
    f4 v = ((const f4*)a)[idx];
    us4 w;
    w.x = f2bf(v.x); w.y = f2bf(v.y); w.z = f2bf(v.z); w.w = f2bf(v.w);
    ((us4*)b)[idx] = w;
}

// ---- Pass A1: per-block bucket histograms ----
__global__ void histA_kernel(const int* __restrict__ uidx, const int* __restrict__ iidx,
                             int* __restrict__ H) {
    __shared__ int hu[NBUK];
    __shared__ int hi[NBUK];
    int tid = threadIdx.x, blk = blockIdx.x;
    for (int b = tid; b < NBUK; b += 256) { hu[b] = 0; hi[b] = 0; }
    __syncthreads();
    int e0 = blk * CHUNK;
    int e1 = e0 + CHUNK; if (e1 > N_EDGES) e1 = N_EDGES;
    for (int e = e0 + tid; e < e1; e += 256) {
        atomicAdd(&hu[uidx[e] >> SH_U], 1);
        atomicAdd(&hi[iidx[e] >> SH_I], 1);
    }
    __syncthreads();
    int* Hb = H + blk * (2 * NBUK);
    for (int b = tid; b < NBUK; b += 256) {
        Hb[b] = hu[b];
        Hb[NBUK + b] = hi[b];
    }
}

// ---- Pass A2: 2-level exclusive scan over logical order ----
__global__ void hscan_tile_kernel(const int* __restrict__ H, int* __restrict__ part) {
    int t = blockIdx.x, tid = threadIdx.x;
    int base = t * HTILE;
    int s = 0;
    for (int i = tid; i < HTILE; i += 256) {
        int L = base + i;
        if (L < HN) s += H[hphys(L)];
    }
    #pragma unroll
    for (int o = 32; o > 0; o >>= 1) s += __shfl_xor(s, o);
    __shared__ int wsum[4];
    if ((tid & 63) == 0) wsum[tid >> 6] = s;
    __syncthreads();
    if (tid == 0) part[t] = wsum[0] + wsum[1] + wsum[2] + wsum[3];
}

__global__ void hscan_write_kernel(const int* __restrict__ H, const int* __restrict__ part,
                                   int* __restrict__ HB) {
    int t = blockIdx.x, tid = threadIdx.x;
    int base = t * HTILE;

    __shared__ int lds[HTILE];
    for (int i = tid; i < HTILE; i += 256) {
        int L = base + i;
        lds[i] = (L < HN) ? H[hphys(L)] : 0;
    }
    __syncthreads();

    int pbase = 0;
    for (int p = 0; p < t; ++p) pbase += part[p];

    int tsum = 0;
    #pragma unroll
    for (int i = 0; i < 16; ++i) tsum += lds[tid * 16 + i];

    int lane = tid & 63, wid = tid >> 6;
    int x = tsum;
    #pragma unroll
    for (int o = 1; o < 64; o <<= 1) {
        int tt = __shfl_up(x, o);
        if (lane >= o) x += tt;
    }
    __shared__ int wsum[4];
    if (lane == 63) wsum[wid] = x;
    __syncthreads();
    int wbase = 0;
    for (int w = 0; w < wid; ++w) wbase += wsum[w];

    int run = pbase + wbase + x - tsum;
    #pragma unroll
    for (int i = 0; i < 16; ++i) {
        int L = base + tid * 16 + i;
        if (L < HN) HB[L] = run;
        run += lds[tid * 16 + i];
    }
}

// ---- Pass A3: scatter edges into bucket-segmented record array ----
__global__ void scatterA_kernel(const int* __restrict__ uidx, const int* __restrict__ iidx,
                                const int* __restrict__ HB, int* __restrict__ rec) {
    __shared__ int cu[NBUK];
    __shared__ int ci[NBUK];
    int tid = threadIdx.x, blk = blockIdx.x;
    for (int sb = tid; sb < 2 * NBUK; sb += 256) {
        int v = HB[sb * B1 + blk];
        if (sb < NBUK) cu[sb] = v; else ci[sb - NBUK] = v;
    }
    __syncthreads();
    int e0 = blk * CHUNK;
    int e1 = e0 + CHUNK; if (e1 > N_EDGES) e1 = N_EDGES;
    for (int e = e0 + tid; e < e1; e += 256) {
        int u = uidx[e];
        int i = iidx[e];
        int pu = atomicAdd(&cu[u >> SH_U], 1);
        rec[pu] = ((u & 511) << 16) | i;
        int pi = atomicAdd(&ci[i >> SH_I], 1);
        rec[pi] = ((i & 255) << 17) | u;
    }
}

// ---- Pass B: per-bucket CSR finalize (byte-offset list) + degree-sorted
// packed slot descriptors: desc[slot] = {absBeg, (rid<<9)|deg}.
__global__ void bucketB_kernel(const int* __restrict__ HB, const int* __restrict__ rec,
                               int* __restrict__ list, int2* __restrict__ desc) {
    int sb = blockIdx.x, tid = threadIdx.x;
    int side = (sb >= NBUK) ? 1 : 0;
    int b = sb - side * NBUK;
    int start = HB[sb * B1];
    int end = (sb == 2 * NBUK - 1) ? 2 * N_EDGES : HB[(sb + 1) * B1];
    int shift = side ? 17 : 16;
    int mask  = side ? 0x1FFFF : 0xFFFF;
    int nd    = side ? 256 : 512;
    int dbase = side ? (b << SH_I) : (b << SH_U);
    int n     = side ? N_ITEMS : N_USERS;

    __shared__ int cnt[512];
    __shared__ int scn[512];
    __shared__ int wsum[4];
    __shared__ int dh[DBINS];
    __shared__ int dsc[DBINS];
    if (tid < 256) { cnt[tid] = 0; cnt[256 + tid] = 0; }
    if (tid < DBINS) dh[tid] = 0;
    __syncthreads();

    for (int r = start + tid; r < end; r += 256)
        atomicAdd(&cnt[rec[r] >> shift], 1);
    __syncthreads();

    int a0 = cnt[2 * tid], a1 = cnt[2 * tid + 1];
    int s = a0 + a1;
    int lane = tid & 63, wid = tid >> 6;
    int x = s;
    #pragma unroll
    for (int o = 1; o < 64; o <<= 1) {
        int tt = __shfl_up(x, o);
        if (lane >= o) x += tt;
    }
    if (lane == 63) wsum[wid] = x;
    __syncthreads();
    int wbase = 0;
    for (int w = 0; w < wid; ++w) wbase += wsum[w];
    int excl = wbase + x - s;
    scn[2 * tid] = excl;
    scn[2 * tid + 1] = excl + a0;
    __syncthreads();

    for (int r = start + tid; r < end; r += 256) {
        int v = rec[r];
        int dl = v >> shift;
        int pos = atomicAdd(&scn[dl], 1);
        list[start + pos] = (v & mask) << 7;   // byte offset of source row
    }
    __syncthreads();                            // scn now holds END offsets

    // ---- in-bucket degree sort -> packed descriptors ----
    int nv = n - dbase; if (nv > nd) nv = nd;
    for (int dl = tid; dl < nv; dl += 256) {
        int d = cnt[dl]; if (d > DBINS - 1) d = DBINS - 1;
        atomicAdd(&dh[d], 1);
    }
    __syncthreads();
    if (tid < DBINS) {
        int v = dh[tid];
        int xx = v;
        #pragma unroll
        for (int o = 1; o < DBINS; o <<= 1) {
            int tt = __shfl_up(xx, o);
            if (tid >= o) xx += tt;
        }
        dsc[tid] = xx - v;
    }
    __syncthreads();
    if (tid < DBINS) dh[tid] = dsc[tid];
    __syncthreads();
    int pwbase = side ? (N_USERS + dbase) : dbase;
    for (int dl = tid; dl < nv; dl += 256) {
        int deg = cnt[dl];
        int d = deg; if (d > DBINS - 1) d = DBINS - 1;
        int p = atomicAdd(&dh[d], 1);
        int absBeg = start + scn[dl] - deg;     // element index into combined list
        int rid = pwbase + dl;                  // combined row id
        desc[pwbase + p] = make_int2(absBeg, (rid << 9) | deg);
    }
}

// ---- Persistent fused gather: 2048 blocks (8/CU resident), each striding
// over slot-chunks within its XCD region. 8 rows per wave, 8 lanes per row.
// Unconditional 16-edge super-batches. Hops 0/1 store bf16 agg; final hop
// fuses out = init + h0 + h1 + y2.
__global__ void gather_norm_v6(const u16* __restrict__ srcU,
                               const u16* __restrict__ srcI,
                               const int* __restrict__ list,
                               const int2* __restrict__ desc,
                               u16* __restrict__ aggU, u16* __restrict__ aggI,
                               const u16* __restrict__ h0U, const u16* __restrict__ h0I,
                               const u16* __restrict__ h1U, const u16* __restrict__ h1I,
                               float* __restrict__ outU, float* __restrict__ outI,
                               const float* __restrict__ initU, const float* __restrict__ initI,
                               int final_hop) {
    int bid = blockIdx.x;
    int xcd = bid & 7;
    int sb0 = bid >> 3;                        // 0..255
    int lane = threadIdx.x & 63;
    int wv = threadIdx.x >> 6;
    int grp = lane >> 3, sub = lane & 7;
    unsigned suboff = (unsigned)(sub << 4);
    int lbase = lane & 56;

    for (int it = sb0; it < XREG; it += 256) {
        int wg = xcd * XREG + it;
        int slot = (wg * 4 + wv) * 8 + grp;

        int beg = 0, deg = 0, rid = 0;
        bool valid = slot < NROWS;
        if (valid) {
            int2 d2 = desc[slot];
            beg = d2.x;
            deg = d2.y & 511;
            rid = d2.y >> 9;
        }
        bool isU = rid < N_USERS;
        int rr = isU ? rid : rid - N_USERS;

        const u16* src  = isU ? srcU : srcI;
        const char* srcB = (const char*)src;
        const int* lp = list + beg;

        float acc[8] = {0.f, 0.f, 0.f, 0.f, 0.f, 0.f, 0.f, 0.f};

        int nfull16 = deg >> 4;                // group-uniform (degree-sorted)
        int e0 = 0;
        for (int b16 = 0; b16 < nfull16; ++b16) {
            int jba = lp[e0 + sub];            // 2 list loads -> 16 edges
            int jbb = lp[e0 + 8 + sub];
            #pragma unroll
            for (int e = 0; e < 8; ++e) {
                unsigned jb = (unsigned)__shfl(jba, lbase | e);
                us8 v = *(const us8*)(srcB + (jb + suboff));
                #pragma unroll
                for (int i = 0; i < 8; ++i) acc[i] += bf2f(v[i]);
            }
            #pragma unroll
            for (int e = 0; e < 8; ++e) {
                unsigned jb = (unsigned)__shfl(jbb, lbase | e);
                us8 v = *(const us8*)(srcB + (jb + suboff));
                #pragma unroll
                for (int i = 0; i < 8; ++i) acc[i] += bf2f(v[i]);
            }
            e0 += 16;
        }
        if (deg & 8) {                         // one unconditional 8-batch
            int jba = lp[e0 + sub];
            #pragma unroll
            for (int e = 0; e < 8; ++e) {
                unsigned jb = (unsigned)__shfl(jba, lbase | e);
                us8 v = *(const us8*)(srcB + (jb + suboff));
                #pragma unroll
                for (int i = 0; i < 8; ++i) acc[i] += bf2f(v[i]);
            }
            e0 += 8;
        }
        int rem = deg & 7;
        if (rem) {                             // single predicated tail batch
            int jba = lp[e0 + sub];            // may over-read into pad (safe)
            #pragma unroll
            for (int e = 0; e < 8; ++e) {
                if (e < rem) {
                    unsigned jb = (unsigned)__shfl(jba, lbase | e);
                    us8 v = *(const us8*)(srcB + (jb + suboff));
                    #pragma unroll
                    for (int i = 0; i < 8; ++i) acc[i] += bf2f(v[i]);
                }
            }
        }

        // ||row||^2 over the 8-lane group
        float q = 0.f;
        #pragma unroll
        for (int i = 0; i < 8; ++i) q += acc[i] * acc[i];
        q += __shfl_xor(q, 1);
        q += __shfl_xor(q, 2);
        q += __shfl_xor(q, 4);
        float inv = 1.f / fmaxf(sqrtf(q), 1e-12f);

        if (valid) {
            size_t ro = (size_t)rr * EMB + (sub << 3);
            if (!final_hop) {
                u16* agg = isU ? aggU : aggI;
                us8 w;
                #pragma unroll
                for (int i = 0; i < 8; ++i) w[i] = f2bf(acc[i] * inv);
                *(us8*)(agg + ro) = w;
            } else {
                const u16* h0 = isU ? h0U : h0I;
                const u16* h1 = isU ? h1U : h1I;
                const float* init = isU ? initU : initI;
                float* out = isU ? outU : outI;
                us8 a = *(const us8*)(h0 + ro);
                us8 b = *(const us8*)(h1 + ro);
                f4 i0 = *(const f4*)(init + ro);
                f4 i1 = *(const f4*)(init + ro + 4);
                f4 r0, r1;
                r0.x = i0.x + bf2f(a[0]) + bf2f(b[0]) + acc[0] * inv;
                r0.y = i0.y + bf2f(a[1]) + bf2f(b[1]) + acc[1] * inv;
                r0.z = i0.z + bf2f(a[2]) + bf2f(b[2]) + acc[2] * inv;
                r0.w = i0.w + bf2f(a[3]) + bf2f(b[3]) + acc[3] * inv;
                r1.x = i1.x + bf2f(a[4]) + bf2f(b[4]) + acc[4] * inv;
                r1.y = i1.y + bf2f(a[5]) + bf2f(b[5]) + acc[5] * inv;
                r1.z = i1.z + bf2f(a[6]) + bf2f(b[6]) + acc[6] * inv;
                r1.w = i1.w + bf2f(a[7]) + bf2f(b[7]) + acc[7] * inv;
                *(f4*)(out + ro)     = r0;
                *(f4*)(out + ro + 4) = r1;
            }
        }
    }
}

extern "C" void kernel_launch(void* const* d_in, const int* in_sizes, int n_in,
                              void* d_out, int out_size, void* d_ws, size_t ws_size,
                              hipStream_t stream) {
    const float* user_emb = (const float*)d_in[0];
    const float* item_emb = (const float*)d_in[1];
    const int*   uidx     = (const int*)d_in[2];
    const int*   iidx     = (const int*)d_in[3];

    float* out      = (float*)d_out;
    float* out_item = out;                           // [N_ITEMS, 64]
    float* out_user = out + (size_t)N_ITEMS * EMB;   // [N_USERS, 64]

    // workspace layout
    u16* ws16    = (u16*)d_ws;
    u16* ua_bf   = ws16;                                   // user agg hop0
    u16* ub_bf   = ua_bf + (size_t)N_USERS * EMB;          // user agg hop1
    u16* ia_bf   = ub_bf + (size_t)N_USERS * EMB;          // item agg hop0
    u16* ib_bf   = ia_bf + (size_t)N_ITEMS * EMB;          // item agg hop1
    u16* uemb_bf = ib_bf + (size_t)N_ITEMS * EMB;
    u16* iemb_bf = uemb_bf + (size_t)N_USERS * EMB;
    int* rec     = (int*)(iemb_bf + (size_t)N_ITEMS * EMB);
    int* list    = rec + 2 * N_EDGES;
    int* H       = list + 2 * N_EDGES + 16;   // +16 pad: staged list tail reads
    int* HB      = H + HN;
    int* part    = HB + HN;
    int2* desc   = (int2*)(part + HTILES + 1);  // 8B aligned region

    // bf16 copies of the embeddings (hop-0 gather sources)
    conv_kernel<<<(NROWS * EMB / 4 + 255) / 256, 256, 0, stream>>>(user_emb, uemb_bf, item_emb, iemb_bf);

    // bucketed CSR build (+ in-bucket degree-sorted packed descriptors)
    histA_kernel<<<B1, 256, 0, stream>>>(uidx, iidx, H);
    hscan_tile_kernel<<<HTILES, 256, 0, stream>>>(H, part);
    hscan_write_kernel<<<HTILES, 256, 0, stream>>>(H, part, HB);
    scatterA_kernel<<<B1, 256, 0, stream>>>(uidx, iidx, HB, rec);
    bucketB_kernel<<<2 * NBUK, 256, 0, stream>>>(HB, rec, list, desc);

    // 3 hops: persistent gather, 2048 blocks (8/CU)
    const int gblocks = 2048;

    gather_norm_v6<<<gblocks, 256, 0, stream>>>(
        iemb_bf, uemb_bf, list, desc,
        ua_bf, ia_bf, nullptr, nullptr, nullptr, nullptr,
        nullptr, nullptr, nullptr, nullptr, 0);

    gather_norm_v6<<<gblocks, 256, 0, stream>>>(
        ia_bf, ua_bf, list, desc,
        ub_bf, ib_bf, nullptr, nullptr, nullptr, nullptr,
        nullptr, nullptr, nullptr, nullptr, 0);

    gather_norm_v6<<<gblocks, 256, 0, stream>>>(
        ib_bf, ub_bf, list, desc,
        nullptr, nullptr, ua_bf, ia_bf, ub_bf, ib_bf,
        out_user, out_item, user_emb, item_emb, 1);
}

// Round 12
// 206.564 us; speedup vs baseline: 1.1127x; 1.1127x over previous
//
#include <hip/hip_runtime.h>

#define N_USERS 100000
#define N_ITEMS 50000
#define NROWS (N_USERS + N_ITEMS)
#define EMB 64
#define N_EDGES 1000000

// ---- bucketed CSR build parameters ----
#define SH_U 9                 // 512 users per bucket
#define SH_I 8                 // 256 items per bucket
#define NBUK 196
#define B1 256
#define CHUNK ((N_EDGES + B1 - 1) / B1)   // 3907
#define HN (2 * NBUK * B1)
#define HTILE 4096
#define HTILES ((HN + HTILE - 1) / HTILE) // 25
#define DBINS 64

// gather schedule: 4688 slot-chunks; user chunks 0..3124, item chunks 3125..4687
#define UCHUNKS 3125
#define TCHUNKS 4688
#define UXCD 3                 // user-side XCDs (items table 6.4MB, good L2 hit)
#define UPER 1042              // ceil(3125/3)
#define IPER 313               // ceil(1563/5)
#define GBLOCKS (8 * UPER)     // 8336

typedef unsigned short u16;
typedef u16 us8 __attribute__((ext_vector_type(8)));
typedef u16 us4 __attribute__((ext_vector_type(4)));
typedef float f4 __attribute__((ext_vector_type(4)));

static __device__ __forceinline__ float bf2f(u16 h) {
    return __uint_as_float(((unsigned)h) << 16);
}
static __device__ __forceinline__ u16 f2bf(float f) {
    unsigned u = __float_as_uint(f);
    return (u16)((u + 0x7FFFu + ((u >> 16) & 1u)) >> 16);
}

static __device__ __forceinline__ int hphys(int L) {
    int sb = L >> 8;
    int blk = L & 255;
    return blk * (2 * NBUK) + sb;
}

// f32 -> bf16, both tables in one launch
__global__ void conv_kernel(const float* __restrict__ ua, u16* __restrict__ ub,
                            const float* __restrict__ ia, u16* __restrict__ ib) {
    const int un4 = N_USERS * EMB / 4;
    const int in4 = N_ITEMS * EMB / 4;
    int t = blockIdx.x * blockDim.x + threadIdx.x;
    const float* a; u16* b; int idx;
    if (t < un4) { a = ua; b = ub; idx = t; }
    else if (t < un4 + in4) { a = ia; b = ib; idx = t - un4; }
    else return;
    f4 v = ((const f4*)a)[idx];
    us4 w;
    w.x = f2bf(v.x); w.y = f2bf(v.y); w.z = f2bf(v.z); w.w = f2bf(v.w);
    ((us4*)b)[idx] = w;
}

// ---- Pass A1: per-block bucket histograms ----
__global__ void histA_kernel(const int* __restrict__ uidx, const int* __restrict__ iidx,
                             int* __restrict__ H) {
    __shared__ int hu[NBUK];
    __shared__ int hi[NBUK];
    int tid = threadIdx.x, blk = blockIdx.x;
    for (int b = tid; b < NBUK; b += 256) { hu[b] = 0; hi[b] = 0; }
    __syncthreads();
    int e0 = blk * CHUNK;
    int e1 = e0 + CHUNK; if (e1 > N_EDGES) e1 = N_EDGES;
    for (int e = e0 + tid; e < e1; e += 256) {
        atomicAdd(&hu[uidx[e] >> SH_U], 1);
        atomicAdd(&hi[iidx[e] >> SH_I], 1);
    }
    __syncthreads();
    int* Hb = H + blk * (2 * NBUK);
    for (int b = tid; b < NBUK; b += 256) {
        Hb[b] = hu[b];
        Hb[NBUK + b] = hi[b];
    }
}

// ---- Pass A2: 2-level exclusive scan over logical order ----
__global__ void hscan_tile_kernel(const int* __restrict__ H, int* __restrict__ part) {
    int t = blockIdx.x, tid = threadIdx.x;
    int base = t * HTILE;
    int s = 0;
    for (int i = tid; i < HTILE; i += 256) {
        int L = base + i;
        if (L < HN) s += H[hphys(L)];
    }
    #pragma unroll
    for (int o = 32; o > 0; o >>= 1) s += __shfl_xor(s, o);
    __shared__ int wsum[4];
    if ((tid & 63) == 0) wsum[tid >> 6] = s;
    __syncthreads();
    if (tid == 0) part[t] = wsum[0] + wsum[1] + wsum[2] + wsum[3];
}

__global__ void hscan_write_kernel(const int* __restrict__ H, const int* __restrict__ part,
                                   int* __restrict__ HB) {
    int t = blockIdx.x, tid = threadIdx.x;
    int base = t * HTILE;

    __shared__ int lds[HTILE];
    for (int i = tid; i < HTILE; i += 256) {
        int L = base + i;
        lds[i] = (L < HN) ? H[hphys(L)] : 0;
    }
    __syncthreads();

    int pbase = 0;
    for (int p = 0; p < t; ++p) pbase += part[p];

    int tsum = 0;
    #pragma unroll
    for (int i = 0; i < 16; ++i) tsum += lds[tid * 16 + i];

    int lane = tid & 63, wid = tid >> 6;
    int x = tsum;
    #pragma unroll
    for (int o = 1; o < 64; o <<= 1) {
        int tt = __shfl_up(x, o);
        if (lane >= o) x += tt;
    }
    __shared__ int wsum[4];
    if (lane == 63) wsum[wid] = x;
    __syncthreads();
    int wbase = 0;
    for (int w = 0; w < wid; ++w) wbase += wsum[w];

    int run = pbase + wbase + x - tsum;
    #pragma unroll
    for (int i = 0; i < 16; ++i) {
        int L = base + tid * 16 + i;
        if (L < HN) HB[L] = run;
        run += lds[tid * 16 + i];
    }
}

// ---- Pass A3: scatter edges into bucket-segmented record array ----
__global__ void scatterA_kernel(const int* __restrict__ uidx, const int* __restrict__ iidx,
                                const int* __restrict__ HB, int* __restrict__ rec) {
    __shared__ int cu[NBUK];
    __shared__ int ci[NBUK];
    int tid = threadIdx.x, blk = blockIdx.x;
    for (int sb = tid; sb < 2 * NBUK; sb += 256) {
        int v = HB[sb * B1 + blk];
        if (sb < NBUK) cu[sb] = v; else ci[sb - NBUK] = v;
    }
    __syncthreads();
    int e0 = blk * CHUNK;
    int e1 = e0 + CHUNK; if (e1 > N_EDGES) e1 = N_EDGES;
    for (int e = e0 + tid; e < e1; e += 256) {
        int u = uidx[e];
        int i = iidx[e];
        int pu = atomicAdd(&cu[u >> SH_U], 1);
        rec[pu] = ((u & 511) << 16) | i;
        int pi = atomicAdd(&ci[i >> SH_I], 1);
        rec[pi] = ((i & 255) << 17) | u;
    }
}

// ---- Pass B: per-bucket CSR finalize (byte-offset list) + degree-sorted
// packed slot descriptors: desc[slot] = {absBeg, (rid<<9)|deg}.
__global__ void bucketB_kernel(const int* __restrict__ HB, const int* __restrict__ rec,
                               int* __restrict__ list, int2* __restrict__ desc) {
    int sb = blockIdx.x, tid = threadIdx.x;
    int side = (sb >= NBUK) ? 1 : 0;
    int b = sb - side * NBUK;
    int start = HB[sb * B1];
    int end = (sb == 2 * NBUK - 1) ? 2 * N_EDGES : HB[(sb + 1) * B1];
    int shift = side ? 17 : 16;
    int mask  = side ? 0x1FFFF : 0xFFFF;
    int nd    = side ? 256 : 512;
    int dbase = side ? (b << SH_I) : (b << SH_U);
    int n     = side ? N_ITEMS : N_USERS;

    __shared__ int cnt[512];
    __shared__ int scn[512];
    __shared__ int wsum[4];
    __shared__ int dh[DBINS];
    __shared__ int dsc[DBINS];
    if (tid < 256) { cnt[tid] = 0; cnt[256 + tid] = 0; }
    if (tid < DBINS) dh[tid] = 0;
    __syncthreads();

    for (int r = start + tid; r < end; r += 256)
        atomicAdd(&cnt[rec[r] >> shift], 1);
    __syncthreads();

    int a0 = cnt[2 * tid], a1 = cnt[2 * tid + 1];
    int s = a0 + a1;
    int lane = tid & 63, wid = tid >> 6;
    int x = s;
    #pragma unroll
    for (int o = 1; o < 64; o <<= 1) {
        int tt = __shfl_up(x, o);
        if (lane >= o) x += tt;
    }
    if (lane == 63) wsum[wid] = x;
    __syncthreads();
    int wbase = 0;
    for (int w = 0; w < wid; ++w) wbase += wsum[w];
    int excl = wbase + x - s;
    scn[2 * tid] = excl;
    scn[2 * tid + 1] = excl + a0;
    __syncthreads();

    for (int r = start + tid; r < end; r += 256) {
        int v = rec[r];
        int dl = v >> shift;
        int pos = atomicAdd(&scn[dl], 1);
        list[start + pos] = (v & mask) << 7;   // byte offset of source row
    }
    __syncthreads();                            // scn now holds END offsets

    // ---- in-bucket degree sort -> packed descriptors ----
    int nv = n - dbase; if (nv > nd) nv = nd;
    for (int dl = tid; dl < nv; dl += 256) {
        int d = cnt[dl]; if (d > DBINS - 1) d = DBINS - 1;
        atomicAdd(&dh[d], 1);
    }
    __syncthreads();
    if (tid < DBINS) {
        int v = dh[tid];
        int xx = v;
        #pragma unroll
        for (int o = 1; o < DBINS; o <<= 1) {
            int tt = __shfl_up(xx, o);
            if (tid >= o) xx += tt;
        }
        dsc[tid] = xx - v;
    }
    __syncthreads();
    if (tid < DBINS) dh[tid] = dsc[tid];
    __syncthreads();
    int pwbase = side ? (N_USERS + dbase) : dbase;
    for (int dl = tid; dl < nv; dl += 256) {
        int deg = cnt[dl];
        int d = deg; if (d > DBINS - 1) d = DBINS - 1;
        int p = atomicAdd(&dh[d], 1);
        int absBeg = start + scn[dl] - deg;     // element index into combined list
        int rid = pwbase + dl;                  // combined row id
        desc[pwbase + p] = make_int2(absBeg, (rid << 9) | deg);
    }
}

// ---- Fused gather (R10 body) with miss-balanced XCD partition:
// user chunks (read 6.4MB item table, ~60% L2 hit) -> XCDs 0-2;
// item chunks (read 12.8MB user table, ~31% L2 hit) -> XCDs 3-7.
// Per-XCD L2-miss load equalized (~16-18MB each vs 33 vs 9 before).
__global__ void gather_norm_v7(const u16* __restrict__ srcU,
                               const u16* __restrict__ srcI,
                               const int* __restrict__ list,
                               const int2* __restrict__ desc,
                               u16* __restrict__ aggU, u16* __restrict__ aggI,
                               const u16* __restrict__ h0U, const u16* __restrict__ h0I,
                               const u16* __restrict__ h1U, const u16* __restrict__ h1I,
                               float* __restrict__ outU, float* __restrict__ outI,
                               const float* __restrict__ initU, const float* __restrict__ initI,
                               int final_hop) {
    int bid = blockIdx.x;
    int xcd = bid & 7;
    int idx = bid >> 3;                        // 0..UPER-1
    int chunk;
    if (xcd < UXCD) {
        chunk = xcd * UPER + idx;              // contiguous per XCD (bucket locality)
        if (chunk >= UCHUNKS) return;
    } else {
        if (idx >= IPER) return;
        chunk = UCHUNKS + (xcd - UXCD) * IPER + idx;
        if (chunk >= TCHUNKS) return;
    }

    int t = chunk * 256 + threadIdx.x;
    int lane = t & 63;
    int grp = lane >> 3, sub = lane & 7;
    int slot = (t >> 6) * 8 + grp;

    int beg = 0, deg = 0, rid = 0;
    bool valid = slot < NROWS;
    if (valid) {
        int2 d2 = desc[slot];
        beg = d2.x;
        deg = d2.y & 511;
        rid = d2.y >> 9;
    }
    bool isU = rid < N_USERS;
    int rr = isU ? rid : rid - N_USERS;

    const u16* src  = isU ? srcU : srcI;
    const char* srcB = (const char*)src;
    unsigned suboff = (unsigned)(sub << 4);
    const int* lp = list + beg;

    float acc[8] = {0.f, 0.f, 0.f, 0.f, 0.f, 0.f, 0.f, 0.f};

    int lbase = lane & 56;                     // grp*8: shfl source base
    int nfull16 = deg >> 4;                    // group-uniform (degree-sorted)
    int e0 = 0;
    for (int b16 = 0; b16 < nfull16; ++b16) {
        int jba = lp[e0 + sub];                // 2 list loads -> 16 edges
        int jbb = lp[e0 + 8 + sub];
        #pragma unroll
        for (int e = 0; e < 8; ++e) {
            unsigned jb = (unsigned)__shfl(jba, lbase | e);
            us8 v = *(const us8*)(srcB + (jb + suboff));
            #pragma unroll
            for (int i = 0; i < 8; ++i) acc[i] += bf2f(v[i]);
        }
        #pragma unroll
        for (int e = 0; e < 8; ++e) {
            unsigned jb = (unsigned)__shfl(jbb, lbase | e);
            us8 v = *(const us8*)(srcB + (jb + suboff));
            #pragma unroll
            for (int i = 0; i < 8; ++i) acc[i] += bf2f(v[i]);
        }
        e0 += 16;
    }
    if (deg & 8) {                             // one unconditional 8-batch
        int jba = lp[e0 + sub];
        #pragma unroll
        for (int e = 0; e < 8; ++e) {
            unsigned jb = (unsigned)__shfl(jba, lbase | e);
            us8 v = *(const us8*)(srcB + (jb + suboff));
            #pragma unroll
            for (int i = 0; i < 8; ++i) acc[i] += bf2f(v[i]);
        }
        e0 += 8;
    }
    int rem = deg & 7;
    if (rem) {                                 // single predicated tail batch
        int jba = lp[e0 + sub];                // may over-read into pad (safe)
        #pragma unroll
        for (int e = 0; e < 8; ++e) {
            if (e < rem) {
                unsigned jb = (unsigned)__shfl(jba, lbase | e);
                us8 v = *(const us8*)(srcB + (jb + suboff));
                #pragma unroll
                for (int i = 0; i < 8; ++i) acc[i] += bf2f(v[i]);
            }
        }
    }

    // ||row||^2 over the 8-lane group
    float q = 0.f;
    #pragma unroll
    for (int i = 0; i < 8; ++i) q += acc[i] * acc[i];
    q += __shfl_xor(q, 1);
    q += __shfl_xor(q, 2);
    q += __shfl_xor(q, 4);
    float inv = 1.f / fmaxf(sqrtf(q), 1e-12f);

    if (!valid) return;
    size_t ro = (size_t)rr * EMB + (sub << 3);

    if (!final_hop) {
        u16* agg = isU ? aggU : aggI;
        us8 w;
        #pragma unroll
        for (int i = 0; i < 8; ++i) w[i] = f2bf(acc[i] * inv);
        *(us8*)(agg + ro) = w;
    } else {
        const u16* h0 = isU ? h0U : h0I;
        const u16* h1 = isU ? h1U : h1I;
        const float* init = isU ? initU : initI;
        float* out = isU ? outU : outI;
        us8 a = *(const us8*)(h0 + ro);
        us8 b = *(const us8*)(h1 + ro);
        f4 i0 = *(const f4*)(init + ro);
        f4 i1 = *(const f4*)(init + ro + 4);
        f4 r0, r1;
        r0.x = i0.x + bf2f(a[0]) + bf2f(b[0]) + acc[0] * inv;
        r0.y = i0.y + bf2f(a[1]) + bf2f(b[1]) + acc[1] * inv;
        r0.z = i0.z + bf2f(a[2]) + bf2f(b[2]) + acc[2] * inv;
        r0.w = i0.w + bf2f(a[3]) + bf2f(b[3]) + acc[3] * inv;
        r1.x = i1.x + bf2f(a[4]) + bf2f(b[4]) + acc[4] * inv;
        r1.y = i1.y + bf2f(a[5]) + bf2f(b[5]) + acc[5] * inv;
        r1.z = i1.z + bf2f(a[6]) + bf2f(b[6]) + acc[6] * inv;
        r1.w = i1.w + bf2f(a[7]) + bf2f(b[7]) + acc[7] * inv;
        *(f4*)(out + ro)     = r0;
        *(f4*)(out + ro + 4) = r1;
    }
}

extern "C" void kernel_launch(void* const* d_in, const int* in_sizes, int n_in,
                              void* d_out, int out_size, void* d_ws, size_t ws_size,
                              hipStream_t stream) {
    const float* user_emb = (const float*)d_in[0];
    const float* item_emb = (const float*)d_in[1];
    const int*   uidx     = (const int*)d_in[2];
    const int*   iidx     = (const int*)d_in[3];

    float* out      = (float*)d_out;
    float* out_item = out;                           // [N_ITEMS, 64]
    float* out_user = out + (size_t)N_ITEMS * EMB;   // [N_USERS, 64]

    // workspace layout
    u16* ws16    = (u16*)d_ws;
    u16* ua_bf   = ws16;                                   // user agg hop0
    u16* ub_bf   = ua_bf + (size_t)N_USERS * EMB;          // user agg hop1
    u16* ia_bf   = ub_bf + (size_t)N_USERS * EMB;          // item agg hop0
    u16* ib_bf   = ia_bf + (size_t)N_ITEMS * EMB;          // item agg hop1
    u16* uemb_bf = ib_bf + (size_t)N_ITEMS * EMB;
    u16* iemb_bf = uemb_bf + (size_t)N_USERS * EMB;
    int* rec     = (int*)(iemb_bf + (size_t)N_ITEMS * EMB);
    int* list    = rec + 2 * N_EDGES;
    int* H       = list + 2 * N_EDGES + 16;   // +16 pad: staged list tail reads
    int* HB      = H + HN;
    int* part    = HB + HN;
    int2* desc   = (int2*)(part + HTILES + 1);  // 8B aligned region

    // bf16 copies of the embeddings (hop-0 gather sources)
    conv_kernel<<<(NROWS * EMB / 4 + 255) / 256, 256, 0, stream>>>(user_emb, uemb_bf, item_emb, iemb_bf);

    // bucketed CSR build (+ in-bucket degree-sorted packed descriptors)
    histA_kernel<<<B1, 256, 0, stream>>>(uidx, iidx, H);
    hscan_tile_kernel<<<HTILES, 256, 0, stream>>>(H, part);
    hscan_write_kernel<<<HTILES, 256, 0, stream>>>(H, part, HB);
    scatterA_kernel<<<B1, 256, 0, stream>>>(uidx, iidx, HB, rec);
    bucketB_kernel<<<2 * NBUK, 256, 0, stream>>>(HB, rec, list, desc);

    // 3 hops: hop0 emb->agg0, hop1 agg0->agg1, hop2 agg1->out (fused final)
    gather_norm_v7<<<GBLOCKS, 256, 0, stream>>>(
        iemb_bf, uemb_bf, list, desc,
        ua_bf, ia_bf, nullptr, nullptr, nullptr, nullptr,
        nullptr, nullptr, nullptr, nullptr, 0);

    gather_norm_v7<<<GBLOCKS, 256, 0, stream>>>(
        ia_bf, ua_bf, list, desc,
        ub_bf, ib_bf, nullptr, nullptr, nullptr, nullptr,
        nullptr, nullptr, nullptr, nullptr, 0);

    gather_norm_v7<<<GBLOCKS, 256, 0, stream>>>(
        ib_bf, ub_bf, list, desc,
        nullptr, nullptr, ua_bf, ia_bf, ub_bf, ib_bf,
        out_user, out_item, user_emb, item_emb, 1);
}